// Round 1
// 283.541 us; speedup vs baseline: 1.0198x; 1.0198x over previous
//
#include <hip/hip_runtime.h>
#include <hip/hip_fp16.h>
#include <math.h>

// Problem constants
#define BB 256
#define LL 256
#define CC 128
#define HIDD 128
#define HH 4
#define DD 32
#define EE 4096
#define NN (BB*CC)          // 32768 nodes
#define LN_EPS 1e-5f

typedef short bf16x8 __attribute__((ext_vector_type(8)));
typedef _Float16 f16x8 __attribute__((ext_vector_type(8)));
typedef float f32x4 __attribute__((ext_vector_type(4)));

// ---------------------------------------------------------------------------
// helpers
// ---------------------------------------------------------------------------
__device__ __forceinline__ float red64(float p) {
    p += __shfl_xor(p, 32);
    p += __shfl_xor(p, 16);
    p += __shfl_xor(p, 8);
    p += __shfl_xor(p, 4);
    p += __shfl_xor(p, 2);
    p += __shfl_xor(p, 1);
    return p;
}
__device__ __forceinline__ unsigned bfr(float f) {        // fp32 -> bf16 bits, RNE
    unsigned x = __float_as_uint(f);
    return (x + 0x7FFFu + ((x >> 16) & 1u)) >> 16;
}
__device__ __forceinline__ unsigned pack2(float a, float b) { return bfr(a) | (bfr(b) << 16); }
__device__ __forceinline__ float b2f(unsigned u) { return __uint_as_float(u << 16); }
__device__ __forceinline__ __half2 u2h(unsigned u) { __half2 r; *(unsigned*)&r = u; return r; }
__device__ __forceinline__ unsigned h2u(__half2 h) { return *(unsigned*)&h; }

// ---------------------------------------------------------------------------
// MFMA GEMM building blocks. LDS tile: 128 rows x 16 chunks (chunk = 8 elems =
// 16B), physical chunk = c ^ (row&7)  -> frag reads are <=2-way conflicts.
// ---------------------------------------------------------------------------
__device__ __forceinline__ void stage_bf16_rm(ushort* lds, const ushort* src, int ldm, int t) {
    #pragma unroll
    for (int i = 0; i < 8; ++i) {
        int flat = i*256 + t;
        int r = flat >> 4, c = flat & 15;
        uint4 pk = *(const uint4*)(src + (size_t)r*ldm + c*8);
        *(uint4*)&lds[((r*16) + (c ^ (r & 7)))*8] = pk;
    }
}
// 128x128x128 tile: 4 waves, each 32 rows x 128 cols (2 m-frags x 8 n-frags)
__device__ __forceinline__ void mfma_tile_128(const ushort* Als, const ushort* Bls,
                                              f32x4 acc[2][8], int w, int lane) {
    int mr = lane & 15, quad = lane >> 4;
    #pragma unroll
    for (int ks = 0; ks < 4; ++ks) {
        int ca = ks*4 + quad;
        bf16x8 a[2], b[8];
        #pragma unroll
        for (int mf = 0; mf < 2; ++mf) {
            int m = w*32 + mf*16 + mr;
            a[mf] = *(const bf16x8*)&Als[((m*16) + (ca ^ (m & 7)))*8];
        }
        #pragma unroll
        for (int nf = 0; nf < 8; ++nf) {
            int n = nf*16 + mr;
            b[nf] = *(const bf16x8*)&Bls[((n*16) + (ca ^ (n & 7)))*8];
        }
        #pragma unroll
        for (int mf = 0; mf < 2; ++mf)
            #pragma unroll
            for (int nf = 0; nf < 8; ++nf)
                acc[mf][nf] = __builtin_amdgcn_mfma_f32_16x16x32_bf16(a[mf], b[nf], acc[mf][nf], 0, 0, 0);
    }
}
#define ZERO_ACC(acc) { _Pragma("unroll") for (int i_=0;i_<2;++i_) { _Pragma("unroll") for (int j_=0;j_<8;++j_) acc[i_][j_] = (f32x4){0.f,0.f,0.f,0.f}; } }

// ---------------------------------------------------------------------------
// K0: weight prep — transpose + bf16-convert all weight matrices.
// ---------------------------------------------------------------------------
__global__ __launch_bounds__(256) void prep_weights(const float* __restrict__ emb_W,
                                                    const float* __restrict__ lWl,
                                                    const float* __restrict__ lWr,
                                                    const float* __restrict__ pW,
                                                    ushort* __restrict__ WembT,
                                                    ushort* __restrict__ WlrT,
                                                    ushort* __restrict__ WpT) {
    int gid = blockIdx.x * 256 + threadIdx.x;
    float v[8];
    if (gid < 4096) {                       // emb: 128 f x 32 l-chunks
        int f = gid >> 5, ch = gid & 31;
        #pragma unroll
        for (int j = 0; j < 8; ++j) v[j] = emb_W[(size_t)(ch*8 + j)*HIDD + f];
        uint4 pk; pk.x = pack2(v[0],v[1]); pk.y = pack2(v[2],v[3]);
        pk.z = pack2(v[4],v[5]); pk.w = pack2(v[6],v[7]);
        *(uint4*)&WembT[(size_t)f*LL + ch*8] = pk;
    } else if (gid < 12288) {               // lin: 4 mats x 128 f x 16 k-chunks
        int g = gid - 4096;
        int mat = g >> 11, f = (g >> 4) & 127, ch = g & 15;
        const float* src = ((mat & 1) ? lWr : lWl) + (size_t)(mat >> 1)*HIDD*HIDD;
        #pragma unroll
        for (int j = 0; j < 8; ++j) v[j] = src[(size_t)(ch*8 + j)*HIDD + f];
        uint4 pk; pk.x = pack2(v[0],v[1]); pk.y = pack2(v[2],v[3]);
        pk.z = pack2(v[4],v[5]); pk.w = pack2(v[6],v[7]);
        *(uint4*)&WlrT[(size_t)mat*HIDD*HIDD + (size_t)f*HIDD + ch*8] = pk;
    } else {                                // proj: 256 l x 16 k-chunks
        int g = gid - 12288;
        int l = g >> 4, ch = g & 15;
        #pragma unroll
        for (int j = 0; j < 8; ++j) v[j] = pW[(size_t)(ch*8 + j)*LL + l];
        uint4 pk; pk.x = pack2(v[0],v[1]); pk.y = pack2(v[2],v[3]);
        pk.z = pack2(v[4],v[5]); pk.w = pack2(v[6],v[7]);
        *(uint4*)&WpT[(size_t)l*HIDD + ch*8] = pk;
    }
}

// ---------------------------------------------------------------------------
// K1: dense log-multiplicity table. lnmT[src][dst] = ln(m) where m = #edges
// (src,dst) + (src==dst ? 1 : 0) [self loops]; -3e4 where m==0.
// exp(l + lnm) = m * exp(l), so dense softmax == segment softmax exactly
// (row-max shift cancels in alpha).
// ---------------------------------------------------------------------------
__global__ __launch_bounds__(256) void build_lnm(const int* __restrict__ edge,
                                                 __half* __restrict__ lnmT) {
    __shared__ int cnt[CC*CC];              // 64KB
    int t = threadIdx.x;
    for (int i = t; i < CC*CC; i += 256) cnt[i] = 0;
    __syncthreads();
    for (int j = t; j < EE; j += 256) {
        int s = edge[j], d = edge[EE + j];
        atomicAdd(&cnt[s*CC + d], 1);
    }
    __syncthreads();
    for (int i = t; i < CC*CC; i += 256) {
        int c = cnt[i] + (((i >> 7) == (i & 127)) ? 1 : 0);
        lnmT[i] = __float2half(c > 0 ? logf((float)c) : -30000.f);
    }
}

// ---------------------------------------------------------------------------
// K2: embedding GEMM (MFMA), fused x-transpose. One block per b.
// ---------------------------------------------------------------------------
__global__ __launch_bounds__(256) void embed_mfma(const float* __restrict__ x,
                                                  const ushort* __restrict__ WembT,
                                                  const float* __restrict__ bias,
                                                  ushort* __restrict__ hout) {
    __shared__ __align__(16) ushort Als[128*16*8];
    __shared__ __align__(16) ushort Bls[128*16*8];
    int b = blockIdx.x;
    int t = threadIdx.x, lane = t & 63, w = t >> 6;
    const float* xb = x + (size_t)b * LL * CC;
    f32x4 acc[2][8];
    ZERO_ACC(acc)
    #pragma unroll
    for (int kh = 0; kh < 2; ++kh) {
        if (kh) __syncthreads();
        #pragma unroll
        for (int i = 0; i < 8; ++i) {
            int flat = i*256 + t;
            int r = flat >> 4, cc = flat & 15;
            float v[8];
            #pragma unroll
            for (int j = 0; j < 8; ++j)
                v[j] = xb[(size_t)(kh*128 + cc*8 + j)*CC + r];
            uint4 pk; pk.x = pack2(v[0],v[1]); pk.y = pack2(v[2],v[3]);
            pk.z = pack2(v[4],v[5]); pk.w = pack2(v[6],v[7]);
            *(uint4*)&Als[((r*16) + (cc ^ (r & 7)))*8] = pk;
        }
        stage_bf16_rm(Bls, WembT + kh*128, LL, t);
        __syncthreads();
        mfma_tile_128(Als, Bls, acc, w, lane);
    }
    int mr = lane & 15, quad = lane >> 4;
    #pragma unroll
    for (int nf = 0; nf < 8; ++nf) {
        int f = nf*16 + mr;
        float bv = bias[f];
        #pragma unroll
        for (int mf = 0; mf < 2; ++mf)
            #pragma unroll
            for (int r = 0; r < 4; ++r) {
                int node = w*32 + mf*16 + quad*4 + r;
                hout[((size_t)b*CC + node)*HIDD + f] = (ushort)bfr(acc[mf][nf][r] + bv);
            }
    }
}

// ---------------------------------------------------------------------------
// K3: xl+xr GEMMs fused (MFMA). Output now fp16 (gat consumes fp16 anyway):
// halves store+load traffic vs fp32.
// ---------------------------------------------------------------------------
__global__ __launch_bounds__(256) void lin_mfma(const ushort* __restrict__ hmat,
                                                const ushort* __restrict__ WlT,
                                                const ushort* __restrict__ WrT,
                                                const float* __restrict__ bl,
                                                const float* __restrict__ br,
                                                __half* __restrict__ xlT,
                                                __half* __restrict__ xrT) {
    __shared__ __align__(16) ushort Als[128*16*8];
    __shared__ __align__(16) ushort Bls[128*16*8];
    int b = blockIdx.x;
    int t = threadIdx.x, lane = t & 63, w = t >> 6;
    int mr = lane & 15, quad = lane >> 4;
    stage_bf16_rm(Als, hmat + (size_t)b*CC*HIDD, HIDD, t);
    #pragma unroll
    for (int lr = 0; lr < 2; ++lr) {
        if (lr) __syncthreads();                     // Bls reuse guard
        stage_bf16_rm(Bls, lr ? WrT : WlT, HIDD, t);
        __syncthreads();
        f32x4 acc[2][8];
        ZERO_ACC(acc)
        mfma_tile_128(Als, Bls, acc, w, lane);
        const float* bias = lr ? br : bl;
        __half* out = lr ? xrT : xlT;
        #pragma unroll
        for (int nf = 0; nf < 8; ++nf) {
            int f = nf*16 + mr;
            float bv = bias[f];
            int h = f >> 5, d = f & 31;
            #pragma unroll
            for (int mf = 0; mf < 2; ++mf)
                #pragma unroll
                for (int r = 0; r < 4; ++r) {
                    int node = w*32 + mf*16 + quad*4 + r;
                    out[(((size_t)b*HH + h)*CC + node)*DD + d] = __float2half(acc[mf][nf][r] + bv);
                }
        }
    }
}

// ---------------------------------------------------------------------------
// K4: DENSE GATv2 attention. One block per (b,h), 256 threads =
// 128 dst x 2 src-halves. Replaces the sparse gather kernel: all LDS reads
// are wave-uniform broadcasts (no random gathers -> no bank conflicts);
// aggregation P @ XL runs on MFMA (f16 in, f32 acc).
//   logit l[dst][src] = 0.6*(Sl[src]+Sr[dst]) + 0.4*sum_k a_k|xl+xr| + ln(m)
//   P = exp(l - rowmax);  out[dst] = (P @ xl) / rowsum;  alpha = P/rowsum.
// ---------------------------------------------------------------------------
__global__ __launch_bounds__(256) void gat_dense(const __half* __restrict__ xl_h,
                                                 const __half* __restrict__ xr_h,
                                                 const __half* __restrict__ lnmT,
                                                 const float* __restrict__ att,
                                                 __half* __restrict__ xagg,
                                                 __half* __restrict__ Pws) {
    __shared__ __align__(16) __half xl_lds[CC*DD];       // 8KB  [src][feat]
    __shared__ __align__(16) __half xlT_swz[DD*16*8];    // 8KB  [feat][chunk^] (MFMA B)
    __shared__ __align__(16) __half P[CC*16*8];          // 32KB [dst][chunk^(dst&7)][8]
    __shared__ float Slq[CC];
    __shared__ float rpart[2][CC];
    __shared__ float spart[2][CC];
    __shared__ float isv[CC];

    int bh = blockIdx.x;                    // b*HH + h
    int h = bh & 3;
    int t = threadIdx.x;
    int sg = t >> 7, dst = t & 127;
    int lane = t & 63, w = t >> 6;

    // stage xl slice (coalesced, 2x uint4 per thread)
    {
        const uint4* sp = (const uint4*)(xl_h + (size_t)bh * CC * DD);
        uint4* dp = (uint4*)xl_lds;
        dp[t] = sp[t];
        dp[t + 256] = sp[t + 256];
    }
    // per-thread: qa2 = 0.4*att (fp16 pairs), xr regs, Srq (independent of LDS)
    __half2 qa2[16], xr2[16];
    const float* ag = att + h*DD;
    #pragma unroll
    for (int c = 0; c < 8; ++c) {
        float4 av = *(const float4*)&ag[c*4];
        qa2[2*c+0] = __floats2half2_rn(0.4f*av.x, 0.4f*av.y);
        qa2[2*c+1] = __floats2half2_rn(0.4f*av.z, 0.4f*av.w);
    }
    float Srq = 0.f;
    {
        uint4 X[4];
        const uint4* xp = (const uint4*)(xr_h + ((size_t)bh*CC + dst)*DD);
        #pragma unroll
        for (int c = 0; c < 4; ++c) X[c] = xp[c];
        const __half2* xv = (const __half2*)X;
        #pragma unroll
        for (int i = 0; i < 16; ++i) {
            xr2[i] = xv[i];
            __half2 p = __hmul2(qa2[i], xr2[i]);
            Srq += __low2float(p) + __high2float(p);
        }
    }
    __syncthreads();

    // Slq[n] = sum_k 0.4*a_k*xl[n,k]   (threads 0..127)
    if (t < CC) {
        uint4 R[4];
        const uint4* rp = (const uint4*)&xl_lds[t*DD];
        #pragma unroll
        for (int c = 0; c < 4; ++c) R[c] = rp[c];
        const __half2* rv = (const __half2*)R;
        __half2 s = __floats2half2_rn(0.f, 0.f);
        #pragma unroll
        for (int i = 0; i < 16; ++i) s = __hfma2(qa2[i], rv[i], s);
        Slq[t] = __low2float(s) + __high2float(s);
    }
    // build transposed+swizzled xl for MFMA B operand: [feat][src-chunk]
    for (int i = t; i < 512; i += 256) {
        int f = i >> 4, c = i & 15;
        __align__(16) __half v[8];
        #pragma unroll
        for (int e = 0; e < 8; ++e) v[e] = xl_lds[(c*8 + e)*DD + f];
        *(uint4*)&xlT_swz[((f*16) + (c ^ (f & 7)))*8] = *(uint4*)v;
    }
    __syncthreads();

    // ---- dense logits: thread (sg,dst) covers src = sg*64 .. sg*64+63 ----
    const __half* lnm_row = lnmT + dst;     // lnmT[src][dst]
    float pmax = -3.0e38f;
    #pragma unroll 2
    for (int jc = 0; jc < 8; ++jc) {
        int chunk = sg*8 + jc;
        __align__(16) __half lv[8];
        #pragma unroll
        for (int e = 0; e < 8; ++e) {
            int src = chunk*8 + e;
            float lnm = __half2float(lnm_row[(size_t)src*CC]);
            uint4 R[4];
            const uint4* rp = (const uint4*)&xl_lds[src*DD];   // wave-uniform: broadcast
            #pragma unroll
            for (int c = 0; c < 4; ++c) R[c] = rp[c];
            const __half2* xv = (const __half2*)R;
            __half2 a0 = __floats2half2_rn(0.f,0.f), a1 = a0, a2 = a0, a3 = a0;
            #pragma unroll
            for (int q = 0; q < 4; ++q) {
                a0 = __hfma2(qa2[4*q+0], __habs2(__hadd2(xv[4*q+0], xr2[4*q+0])), a0);
                a1 = __hfma2(qa2[4*q+1], __habs2(__hadd2(xv[4*q+1], xr2[4*q+1])), a1);
                a2 = __hfma2(qa2[4*q+2], __habs2(__hadd2(xv[4*q+2], xr2[4*q+2])), a2);
                a3 = __hfma2(qa2[4*q+3], __habs2(__hadd2(xv[4*q+3], xr2[4*q+3])), a3);
            }
            __half2 ts = __hadd2(__hadd2(a0, a1), __hadd2(a2, a3));
            float T = __low2float(ts) + __high2float(ts);
            float l = fmaf(1.5f, Slq[src] + Srq, T) + lnm;
            pmax = fmaxf(pmax, l);
            lv[e] = __float2half(l);
        }
        *(uint4*)&P[((dst*16) + (chunk ^ (dst & 7)))*8] = *(uint4*)lv;
    }

    // ---- row softmax (two src-halves combine via LDS) ----
    rpart[sg][dst] = pmax;
    __syncthreads();
    float m = fmaxf(rpart[0][dst], rpart[1][dst]);
    float ssum = 0.f;
    #pragma unroll
    for (int jc = 0; jc < 8; ++jc) {
        int chunk = sg*8 + jc;
        uint4* slot = (uint4*)&P[((dst*16) + (chunk ^ (dst & 7)))*8];
        uint4 u = *slot;
        __half2* ph = (__half2*)&u;
        #pragma unroll
        for (int i = 0; i < 4; ++i) {
            float e0 = __expf(__low2float(ph[i]) - m);
            float e1 = __expf(__high2float(ph[i]) - m);
            ssum += e0 + e1;
            ph[i] = __floats2half2_rn(e0, e1);
        }
        *slot = u;
    }
    spart[sg][dst] = ssum;
    __syncthreads();
    if (sg == 0) isv[dst] = 1.f / (spart[0][dst] + spart[1][dst] + 1e-16f);
    __syncthreads();

    // ---- aggregation on MFMA: out[dst][feat] = (P @ xl) * is[dst] ----
    int mr = lane & 15, quad = lane >> 4;
    f32x4 acc[2][2];
    #pragma unroll
    for (int i = 0; i < 2; ++i)
        #pragma unroll
        for (int j = 0; j < 2; ++j) acc[i][j] = (f32x4){0.f,0.f,0.f,0.f};
    #pragma unroll
    for (int ks = 0; ks < 4; ++ks) {
        int ca = ks*4 + quad;
        f16x8 a[2], bfrag[2];
        #pragma unroll
        for (int mf = 0; mf < 2; ++mf) {
            int mm = w*32 + mf*16 + mr;
            a[mf] = *(const f16x8*)&P[((mm*16) + (ca ^ (mm & 7)))*8];
        }
        #pragma unroll
        for (int nf = 0; nf < 2; ++nf) {
            int nn = nf*16 + mr;
            bfrag[nf] = *(const f16x8*)&xlT_swz[((nn*16) + (ca ^ (nn & 7)))*8];
        }
        #pragma unroll
        for (int mf = 0; mf < 2; ++mf)
            #pragma unroll
            for (int nf = 0; nf < 2; ++nf)
                acc[mf][nf] = __builtin_amdgcn_mfma_f32_16x16x32_f16(a[mf], bfrag[nf], acc[mf][nf], 0, 0, 0);
    }
    {
        int b = bh >> 2;
        #pragma unroll
        for (int mf = 0; mf < 2; ++mf)
            #pragma unroll
            for (int r = 0; r < 4; ++r) {
                int drow = w*32 + mf*16 + quad*4 + r;
                float is = isv[drow];
                #pragma unroll
                for (int nf = 0; nf < 2; ++nf) {
                    int f = nf*16 + mr;
                    xagg[(((size_t)b*CC + drow)*HH + h)*DD + f] =
                        __float2half(acc[mf][nf][r] * is);
                }
            }
    }

    // ---- layer-1: dump alpha (normalized P) for the attention map ----
    if (Pws) {
        __half* pg = Pws + (size_t)bh * CC * CC;
        for (int i = t; i < CC*CC/2; i += 256) {
            int dd = i >> 6, sp = i & 63;
            int src = sp*2;
            int chunk = (src >> 3) ^ (dd & 7);
            __half2 v = *(const __half2*)&P[((dd*16) + chunk)*8 + (src & 7)];
            float is = isv[dd];
            *(__half2*)&pg[dd*CC + src] =
                __floats2half2_rn(__low2float(v)*is, __high2float(v)*is);
        }
    }
}

// ---------------------------------------------------------------------------
// K5: per-node epilogue (2 nodes/block): bias -> ELU -> residual -> LayerNorm
// in-place on bf16 h; (layer 1) attn row = 0.25 * sum_h Pws — fully coalesced,
// no CSR, no atomics.
// ---------------------------------------------------------------------------
__global__ __launch_bounds__(256) void gat_epilogue(const __half* __restrict__ xagg,
                                                    const float* __restrict__ gbias,
                                                    const float* __restrict__ ln_g,
                                                    const float* __restrict__ ln_b,
                                                    const __half* __restrict__ Pws,
                                                    ushort* __restrict__ hmat,
                                                    float* __restrict__ attn_out) {
    __shared__ float wred[4], wred2[4];
    int t = threadIdx.x;
    int nl = t >> 7, f = t & 127;
    int node = blockIdx.x*2 + nl;
    int b = node >> 7, dstc = node & 127;

    float o = __half2float(xagg[(size_t)node*HIDD + f]) + gbias[f];
    o = o > 0.f ? o : (__expf(o) - 1.f);
    float hv = b2f((unsigned)hmat[(size_t)node*HIDD + f]) + o;

    float sum = red64(hv);
    if ((t & 63) == 0) wred[t >> 6] = sum;
    __syncthreads();
    float mean = (wred[nl*2] + wred[nl*2+1]) * 0.0078125f;
    float d = hv - mean;
    float q = red64(d * d);
    if ((t & 63) == 0) wred2[t >> 6] = q;
    __syncthreads();
    float var = (wred2[nl*2] + wred2[nl*2+1]) * 0.0078125f;
    hmat[(size_t)node*HIDD + f] = (ushort)bfr(d * rsqrtf(var + LN_EPS) * ln_g[f] + ln_b[f]);

    if (attn_out) {
        float a = 0.f;
        #pragma unroll
        for (int hh = 0; hh < HH; ++hh)
            a += __half2float(Pws[(((size_t)(b*HH + hh)*CC) + dstc)*CC + f]);
        attn_out[(size_t)node*CC + f] = 0.25f * a;
    }
}

// ---------------------------------------------------------------------------
// K6: projection GEMM (MFMA) with fused output transpose.
// ---------------------------------------------------------------------------
__global__ __launch_bounds__(256) void proj_mfma(const ushort* __restrict__ hmat,
                                                 const ushort* __restrict__ WpT,
                                                 const float* __restrict__ bias,
                                                 float* __restrict__ out) {
    __shared__ __align__(16) ushort Als[128*16*8];
    __shared__ __align__(16) ushort Bls[128*16*8];
    int l0 = blockIdx.x * 128;
    int b  = blockIdx.y;
    int t = threadIdx.x, lane = t & 63, w = t >> 6;
    f32x4 acc[2][8];
    ZERO_ACC(acc)
    stage_bf16_rm(Als, WpT + (size_t)l0*HIDD, HIDD, t);
    stage_bf16_rm(Bls, hmat + (size_t)b*CC*HIDD, HIDD, t);
    __syncthreads();
    mfma_tile_128(Als, Bls, acc, w, lane);
    int mr = lane & 15, quad = lane >> 4;
    #pragma unroll
    for (int nf = 0; nf < 8; ++nf) {
        int c = nf*16 + mr;
        #pragma unroll
        for (int mf = 0; mf < 2; ++mf)
            #pragma unroll
            for (int r = 0; r < 4; ++r) {
                int l = l0 + w*32 + mf*16 + quad*4 + r;
                out[((size_t)b*LL + l)*CC + c] = acc[mf][nf][r] + bias[l];
            }
    }
}

// ---------------------------------------------------------------------------
extern "C" void kernel_launch(void* const* d_in, const int* in_sizes, int n_in,
                              void* d_out, int out_size, void* d_ws, size_t ws_size,
                              hipStream_t stream) {
    const float* x        = (const float*)d_in[0];
    const int*   edge     = (const int*)d_in[1];
    const float* emb_W    = (const float*)d_in[2];
    const float* emb_b    = (const float*)d_in[3];
    const float* lin_l_W  = (const float*)d_in[4];
    const float* lin_l_b  = (const float*)d_in[5];
    const float* lin_r_W  = (const float*)d_in[6];
    const float* lin_r_b  = (const float*)d_in[7];
    const float* att      = (const float*)d_in[8];
    const float* gat_bias = (const float*)d_in[9];
    const float* ln_g     = (const float*)d_in[10];
    const float* ln_b     = (const float*)d_in[11];
    const float* proj_W   = (const float*)d_in[12];
    const float* proj_b   = (const float*)d_in[13];

    // workspace: h(bf16) | xl(fp16) | xr(fp16) | xagg(fp16) | Pws(fp16) | lnm | W
    ushort* h     = (ushort*)d_ws;
    __half* xl_h  = (__half*)(h + (size_t)NN * HIDD);
    __half* xr_h  = xl_h + (size_t)NN * HIDD;
    __half* xagg  = xr_h + (size_t)NN * HIDD;
    __half* Pws   = xagg + (size_t)NN * HIDD;
    __half* lnmT  = Pws + (size_t)BB * HH * CC * CC;
    ushort* WembT = (ushort*)(lnmT + (size_t)CC * CC);
    ushort* WlrT  = WembT + (size_t)CC*LL;
    ushort* WpT   = WlrT + (size_t)4*HIDD*HIDD;

    float* out0 = (float*)d_out;                       // (B, L, C)
    float* attn = out0 + (size_t)BB * LL * CC;         // (B, C, C)

    build_lnm<<<1, 256, 0, stream>>>(edge, lnmT);
    prep_weights<<<64, 256, 0, stream>>>(emb_W, lin_l_W, lin_r_W, proj_W, WembT, WlrT, WpT);
    embed_mfma<<<BB, 256, 0, stream>>>(x, WembT, emb_b, h);
    for (int layer = 0; layer < 2; ++layer) {
        lin_mfma<<<BB, 256, 0, stream>>>(h,
            WlrT + (size_t)(layer*2 + 0)*HIDD*HIDD,
            WlrT + (size_t)(layer*2 + 1)*HIDD*HIDD,
            lin_l_b + layer*HIDD, lin_r_b + layer*HIDD,
            xl_h, xr_h);
        gat_dense<<<BB*HH, 256, 0, stream>>>(xl_h, xr_h, lnmT,
            att + layer*HIDD, xagg, (layer == 1) ? Pws : nullptr);
        gat_epilogue<<<NN/2, 256, 0, stream>>>(xagg,
            gat_bias + layer*HIDD, ln_g + layer*HIDD, ln_b + layer*HIDD,
            (layer == 1) ? Pws : nullptr, h, (layer == 1) ? attn : nullptr);
    }
    proj_mfma<<<dim3(2, BB), 256, 0, stream>>>(h, WpT, proj_b, out0);
}